// Round 12
// baseline (1172.113 us; speedup 1.0000x reference)
//
#include <hip/hip_runtime.h>
#include <hip/hip_bf16.h>

#define D_MODEL 256
#define D_STATE 64
#define MCON    64
#define TLEN    1024
#define BATCH   4
#define NEG_INF -1e9f
#define PT      4      // tokens per proj block (1024 blocks = 4/CU — R25-proven)
#define ZT      4      // tokens per zout block (1024 blocks = 4/CU — R24-proven)

// LDS-ordered workgroup barrier (no vmcnt drain)
#define BAR() asm volatile("s_waitcnt lgkmcnt(0)\n\ts_barrier" ::: "memory")

// ---------------- DPP wave-64 helpers ----------------
template <int CTRL, int RM>
__device__ __forceinline__ float dpp_f(float x) {
    int xi = __float_as_int(x);
    int r  = __builtin_amdgcn_update_dpp(xi, xi, CTRL, RM, 0xf, false);
    return __int_as_float(r);
}
__device__ __forceinline__ float bcast_lane(float x, int lane) {
    return __int_as_float(__builtin_amdgcn_readlane(__float_as_int(x), lane));
}
__device__ __forceinline__ float wave_sum(float x) {
    x += dpp_f<0x111, 0xf>(x);
    x += dpp_f<0x112, 0xf>(x);
    x += dpp_f<0x114, 0xf>(x);
    x += dpp_f<0x118, 0xf>(x);
    x += dpp_f<0x142, 0xa>(x);
    x += dpp_f<0x143, 0xc>(x);
    return bcast_lane(x, 63);
}
__device__ __forceinline__ float wave_max(float x) {
    x = fmaxf(x, dpp_f<0x111, 0xf>(x));
    x = fmaxf(x, dpp_f<0x112, 0xf>(x));
    x = fmaxf(x, dpp_f<0x114, 0xf>(x));
    x = fmaxf(x, dpp_f<0x118, 0xf>(x));
    x = fmaxf(x, dpp_f<0x142, 0xa>(x));
    x = fmaxf(x, dpp_f<0x143, 0xc>(x));
    return bcast_lane(x, 63);
}
// exact argmax with first-index tiebreak (validated R14/R15)
__device__ __forceinline__ int wave_argmax_fast(float lg, float mx) {
    const unsigned long long m = __ballot(lg == mx);
    return (int)(__ffsll((long long)m) - 1);
}
// quad_perm [1,0,3,2]
__device__ __forceinline__ float dpp_swap1(float x) {
    int xi = __float_as_int(x);
    return __int_as_float(__builtin_amdgcn_update_dpp(xi, xi, 0xB1, 0xf, 0xf, false));
}

// ---------------------------------------------------------------------------
// Kernel 1: projections, token-tiled (PT=4 = 1024 blocks, 4/CU). Unchanged
// from R25 -> bit-identical outputs.
// ---------------------------------------------------------------------------
__global__ __launch_bounds__(256) void proj_kernel(
    const float* __restrict__ x,
    const float* __restrict__ Wq, const float* __restrict__ bq,
    const float* __restrict__ Wk, const float* __restrict__ bk,
    const float* __restrict__ Wv, const float* __restrict__ bv,
    float* __restrict__ q_ws, float* __restrict__ k_ws, float* __restrict__ v_ws)
{
    const int tok0 = blockIdx.x * PT;
    const int tid  = threadIdx.x;
    __shared__ float sx[PT][D_MODEL];   // 4 KB

    #pragma unroll
    for (int tt = 0; tt < PT; ++tt)
        sx[tt][tid] = x[(size_t)(tok0 + tt) * D_MODEL + tid];
    __syncthreads();

    // v = x @ Wv + bv
    {
        float acc[PT];
        #pragma unroll
        for (int tt = 0; tt < PT; ++tt) acc[tt] = 0.f;
        for (int i = 0; i < D_MODEL; ++i) {
            const float w = Wv[i * D_MODEL + tid];
            #pragma unroll
            for (int tt = 0; tt < PT; ++tt) acc[tt] += sx[tt][i] * w;
        }
        const float bvi = bv[tid];
        #pragma unroll
        for (int tt = 0; tt < PT; ++tt)
            v_ws[(size_t)(tok0 + tt) * D_MODEL + tid] = acc[tt] + bvi;
    }

    // q (wave 0) / k (wave 1), l2-normalized per token
    if (tid < 128) {
        const int j = tid & 63;
        const float* W  = (tid < 64) ? Wq : Wk;
        const float* bb = (tid < 64) ? bq : bk;
        float a[PT];
        #pragma unroll
        for (int tt = 0; tt < PT; ++tt) a[tt] = 0.f;
        for (int i = 0; i < D_MODEL; ++i) {
            const float w = W[i * D_STATE + j];
            #pragma unroll
            for (int tt = 0; tt < PT; ++tt) a[tt] += sx[tt][i] * w;
        }
        const float bbj = bb[j];
        #pragma unroll
        for (int tt = 0; tt < PT; ++tt) {
            const float av = a[tt] + bbj;
            float s2 = av * av;
            #pragma unroll
            for (int off = 1; off < 64; off <<= 1) s2 += __shfl_xor(s2, off, 64);
            const float nrm = fmaxf(sqrtf(s2), 1e-12f);
            const float o = av / nrm;
            if (tid < 64) q_ws[(size_t)(tok0 + tt) * D_STATE + j] = o;
            else          k_ws[(size_t)(tok0 + tt) * D_STATE + j] = o;
        }
    }
}

// ---------------------------------------------------------------------------
// Kernel 2: scan. R26 (resubmitted R27): bulk waves read q/k from GLOBAL
// into two named register buffer sets (bufA = even t, bufB = odd t; t-loop
// unrolled by 2 -> NO register rotation). Prefetch for t+2 issued at t ->
// ~2 iterations (~1300 cy) of slack, exceeding cold-HBM latency. k_t copied
// to kpR before the overwriting prefetch (rebuild at t+1 needs it).
// sQ/sK LDS staging deleted -> ~32 ds_read_b128/iter off the LDS port.
// Identical bytes from q_ws/k_ws -> bit-identical trajectory.
// ---------------------------------------------------------------------------
__global__ __launch_bounds__(256) void scan_kernel(
    const float* __restrict__ q_ws, const float* __restrict__ k_ws,
    const float* __restrict__ v_ws,
    float* __restrict__ sims_ws, int* __restrict__ n_ws,
    int* __restrict__ ver_ws, float* __restrict__ vlog_ws,
    const float* __restrict__ ls_p)
{
    const int b   = blockIdx.x;
    const int tid = threadIdx.x;
    const int l   = tid & 63;
    const int wv  = tid >> 6;
    const float scale = fminf(expf(ls_p[0]), 100.f);

    __shared__ __align__(16) float sV[MCON * D_MODEL];   // values (wave1 only)
    __shared__ __align__(16) float sBuf[2][MCON];        // bulkdot (sims_{t+1})
    __shared__ __align__(16) float sS2[2][MCON];         // sum(tmp^2) per row
    __shared__ float sFA[2];                             // f_add = k_t . q_{t+1}
    __shared__ int   sFlagChg[2];
    __shared__ int   sFlagUpd[2];

    const float4 zero4 = make_float4(0.f, 0.f, 0.f, 0.f);
    #pragma unroll
    for (int i = 0; i < 16; ++i) ((float4*)sV)[i * 256 + tid] = zero4;
    if (tid < MCON) { sBuf[0][tid] = 0.f; sS2[0][tid] = 0.f; }
    if (tid == 0) { sFA[0] = 0.f; sFlagChg[0] = -1; sFlagUpd[0] = 0; }

    const float* qg = q_ws + b * TLEN * D_STATE;
    const float* kg = k_ws + b * TLEN * D_STATE;
    const float* vg = v_ws + b * TLEN * D_MODEL;
    float* vlog_b   = vlog_ws + (size_t)b * (TLEN + 1) * D_MODEL;

    if (tid < 64) {
        *(float4*)&vlog_b[4 * l] = zero4;   // vlog slot 0 = zeros
    }

    float qcur = 0.f, kcur = 0.f, qnx2 = 0.f, knx = 0.f;
    float fa_prev = 0.f;                    // wave0: fa posted at t-1 (== sFA[pc])
    int   n0 = 0, ver0 = 0;                 // wave0: replicated bookkeeping
    if (wv == 0) {
        kcur = kg[l];
        qcur = qg[D_STATE + l];
        knx  = kg[D_STATE + l];
        qnx2 = qg[2 * D_STATE + l];
    }
    float  cnt_l = 0.f;
    int    n = 0, chg_prev = -1, upd_prev = 0;
    float4 vvt = zero4;
    if (wv == 1) vvt = *(const float4*)&vg[4 * l];   // v_0
    const int brow = ((wv - 2) << 5) + (l >> 1);
    const int bh   = l & 1;
    float4 Creg[8];
    float4 tprev[8], kpR[8];
    float4 qbA[8], kbA[8], qbB[8], kbB[8];
    float  s2prev = 0.f;
    #pragma unroll
    for (int c = 0; c < 8; ++c) {
        Creg[c] = zero4; tprev[c] = zero4; kpR[c] = zero4;
        qbA[c] = zero4; kbA[c] = zero4; qbB[c] = zero4; kbB[c] = zero4;
    }
    if (wv >= 2) {
        // preload: bufA = {q_1, k_0} (t=0), bufB = {q_2, k_1} (t=1)
        const float* qG1 = qg + D_STATE + 32 * bh;
        const float* kG0 = kg + 32 * bh;
        const float* qG2 = qg + 2 * D_STATE + 32 * bh;
        const float* kG1 = kg + D_STATE + 32 * bh;
        #pragma unroll
        for (int c = 0; c < 8; ++c) {
            qbA[c] = *(const float4*)(qG1 + 4 * c);
            kbA[c] = *(const float4*)(kG0 + 4 * c);
            qbB[c] = *(const float4*)(qG2 + 4 * c);
            kbB[c] = *(const float4*)(kG1 + 4 * c);
        }
    }

    __syncthreads();

    auto iter = [&](int t, float4 (&qb)[8], float4 (&kb)[8]) {
        const int token = b * TLEN + t;
        const int pc = t & 1, pn = 1 - pc;

        if (wv >= 2) {
            const int  chg  = sFlagChg[pc];
            const bool updf = sFlagUpd[pc] != 0;
            if (chg == brow) {
                const float rn = 1.f / fmaxf(sqrtf(s2prev), 1e-12f);
                #pragma unroll
                for (int c = 0; c < 8; ++c) {
                    Creg[c].x = updf ? tprev[c].x * rn : kpR[c].x;
                    Creg[c].y = updf ? tprev[c].y * rn : kpR[c].y;
                    Creg[c].z = updf ? tprev[c].z * rn : kpR[c].z;
                    Creg[c].w = updf ? tprev[c].w * rn : kpR[c].w;
                }
            }
            float pa = 0.f, pb = 0.f, sa = 0.f, sb = 0.f;
            #pragma unroll
            for (int c = 0; c < 8; ++c) {
                const float4 c4 = Creg[c];
                const float4 q4 = qb[c];
                const float4 k4 = kb[c];
                float4 t4;
                t4.x = 0.9f * c4.x + 0.1f * k4.x;
                t4.y = 0.9f * c4.y + 0.1f * k4.y;
                t4.z = 0.9f * c4.z + 0.1f * k4.z;
                t4.w = 0.9f * c4.w + 0.1f * k4.w;
                if (c < 4) {
                    pa += c4.x * q4.x; pa += c4.y * q4.y;
                    pa += c4.z * q4.z; pa += c4.w * q4.w;
                    sa += t4.x * t4.x; sa += t4.y * t4.y;
                    sa += t4.z * t4.z; sa += t4.w * t4.w;
                } else {
                    pb += c4.x * q4.x; pb += c4.y * q4.y;
                    pb += c4.z * q4.z; pb += c4.w * q4.w;
                    sb += t4.x * t4.x; sb += t4.y * t4.y;
                    sb += t4.z * t4.z; sb += t4.w * t4.w;
                }
                tprev[c] = t4;
            }
            const float sd  = pa + pb;
            const float dot = sd + dpp_swap1(sd);
            const float ss  = sa + sb;
            const float s2  = ss + dpp_swap1(ss);
            s2prev = s2;
            if (bh == 0) { sBuf[pn][brow] = dot; sS2[pn][brow] = s2; }

            // preserve k_t for t+1's rebuild, THEN issue prefetch for t+2
            // into this named buffer (first use two iterations away)
            #pragma unroll
            for (int c = 0; c < 8; ++c) kpR[c] = kb[c];
            const int qidx = (t + 3 < TLEN) ? t + 3 : TLEN - 1;
            const int kidx = (t + 2 < TLEN) ? t + 2 : TLEN - 1;
            const float* qG = qg + qidx * D_STATE + 32 * bh;
            const float* kG = kg + kidx * D_STATE + 32 * bh;
            #pragma unroll
            for (int c = 0; c < 8; ++c) {
                qb[c] = *(const float4*)(qG + 4 * c);
                kb[c] = *(const float4*)(kG + 4 * c);
            }
        }

        if (wv == 0) {
            // ---- replicated sims/ver/n bookkeeping + stores (R22) ----
            const int chg0 = sFlagChg[pc];
            const int upd0 = sFlagUpd[pc];
            n0  += (chg0 >= 0 && upd0 == 0) ? 1 : 0;     // do_add at t-1
            if (l == chg0) ver0 = t;                     // ver set at t-1 -> t
            const float bufv0 = sBuf[pc][l];
            const int   ip0   = (chg0 < 0) ? 0 : chg0;
            const float s2v0  = sS2[pc][ip0];
            const float bdc0  = bcast_lane(bufv0, ip0);
            const float fupd0 = (0.9f * bdc0 + 0.1f * fa_prev)
                                / fmaxf(sqrtf(s2v0), 1e-12f);
            const float fsim0 = upd0 ? fupd0 : fa_prev;
            const float simv0 = (l == chg0) ? fsim0 : bufv0;
            sims_ws[(size_t)token * MCON + l] = simv0;
            ver_ws[(size_t)token * MCON + l]  = ver0;
            if (l == 0) n_ws[token] = n0;

            // ---- original wave0 work (staging writes removed — R26) ----
            const float fa = wave_sum(kcur * qcur);
            if (l == 0) sFA[pn] = fa;
            fa_prev = fa;
            kcur = knx; qcur = qnx2;
            const int tk2 = (t + 2 < TLEN) ? t + 2 : TLEN - 1;
            const int tq3 = (t + 3 < TLEN) ? t + 3 : TLEN - 1;
            knx  = kg[tk2 * D_STATE + l];
            qnx2 = qg[tq3 * D_STATE + l];
        }

        if (wv == 1) {
            // copy arrived v_t out, then issue v_{t+1} load FIRST (R20)
            const float4 vt = vvt;
            const int tk = (t + 1 < TLEN) ? t + 1 : t;
            vvt = *(const float4*)&vg[tk * D_MODEL + 4 * l];

            const int   ip   = (chg_prev < 0) ? 0 : chg_prev;
            const float bufv = sBuf[pc][l];

            // R25: DPP max on bufv lanes runs parallel to the fupd chain
            const float lgO = ((l < n && l != chg_prev) ? bufv : NEG_INF) * scale;
            const float mxO = wave_max(lgO);

            const float s2v  = sS2[pc][ip];
            const float fa   = sFA[pc];
            const float bdc  = bcast_lane(bufv, ip);
            const float fupd = (0.9f * bdc + 0.1f * fa)
                               / fmaxf(sqrtf(s2v), 1e-12f);
            const float fsim = upd_prev ? fupd : fa;          // wave-uniform
            const float simv = (l == chg_prev) ? fsim : bufv;

            const float lgC = ((chg_prev >= 0) ? fsim : NEG_INF) * scale;
            const float mx  = fmaxf(mxO, lgC);
            const float lg  = ((l < n) ? simv : NEG_INF) * scale;
            const int   sel    = wave_argmax_fast(lg, mx);
            const float selSim = bcast_lane(simv,  sel);
            const float cnt    = bcast_lane(cnt_l, sel);

            const float4 vs = *(const float4*)&sV[sel * D_MODEL + 4 * l];
            float r = (vs.x - vt.x) * (vs.x - vt.x)
                    + (vs.y - vt.y) * (vs.y - vt.y)
                    + (vs.z - vt.z) * (vs.z - vt.z)
                    + (vs.w - vt.w) * (vs.w - vt.w);
            const float residual = sqrtf(wave_sum(r) * (1.f / 256.f));

            const bool has = n > 0;
            const bool refine = has && (n < MCON) &&
                                (selSim < 0.75f || residual > 1.0f);
            const bool do_add    = ((!has) || refine) && (n < MCON);
            const bool do_update = has && !refine;
            const int  chg = do_update ? sel : n;

            float4 nv;
            nv.x = (vs.x * cnt + vt.x) / (cnt + 1.f);
            nv.y = (vs.y * cnt + vt.y) / (cnt + 1.f);
            nv.z = (vs.z * cnt + vt.z) / (cnt + 1.f);
            nv.w = (vs.w * cnt + vt.w) / (cnt + 1.f);
            float4 valV;
            valV.x = do_update ? nv.x : vt.x;
            valV.y = do_update ? nv.y : vt.y;
            valV.z = do_update ? nv.z : vt.z;
            valV.w = do_update ? nv.w : vt.w;
            *(float4*)&sV[chg * D_MODEL + 4 * l] = valV;
            *(float4*)&vlog_b[(size_t)(t + 1) * D_MODEL + 4 * l] = valV;

            if (l == 0) { sFlagChg[pn] = chg; sFlagUpd[pn] = do_update ? 1 : 0; }

            if (l == sel && do_update) cnt_l = cnt + 1.f;
            if (l == n   && do_add)    cnt_l = 1.f;
            n += do_add ? 1 : 0;
            chg_prev = chg; upd_prev = do_update ? 1 : 0;
        }

        BAR();
    };

    for (int t2 = 0; t2 < TLEN; t2 += 2) {
        iter(t2,     qbA, kbA);
        iter(t2 + 1, qbB, kbB);
    }
}

// ---------------------------------------------------------------------------
// Kernel 3: fused payload, token-tiled (ZT=4 = 1024 blocks, 4/CU).
// Unchanged from R25 -> bit-identical.
// ---------------------------------------------------------------------------
__global__ __launch_bounds__(256) void zout_kernel(
    const float* __restrict__ sims_ws, const int* __restrict__ n_ws,
    const int* __restrict__ ver_ws, const float* __restrict__ vlog_ws,
    const float* __restrict__ Wo, const float* __restrict__ bo,
    float* __restrict__ out, const float* __restrict__ ls_p)
{
    const int tok0 = blockIdx.x * ZT;
    const int b    = tok0 >> 10;             // ZT divides TLEN -> same seq
    const int tid  = threadIdx.x;
    const int l    = tid & 63;
    const int wv   = tid >> 6;
    const float scale = fminf(expf(ls_p[0]), 100.f);

    __shared__ float sWt[ZT][MCON];
    __shared__ int   sVer[ZT][MCON];
    __shared__ int   sN[ZT];
    __shared__ float sy[ZT][D_MODEL];

    for (int tt = wv; tt < ZT; tt += 4) {
        const int token = tok0 + tt;
        const int nt = n_ws[token];
        if (l == 0) sN[tt] = nt;
        sVer[tt][l] = ver_ws[(size_t)token * MCON + l];
        const float simv = sims_ws[(size_t)token * MCON + l];
        const float lg = ((l < nt) ? simv : NEG_INF) * scale;
        const float mx = wave_max(lg);
        const float e  = expf(lg - mx);
        const float sm = wave_sum(e);
        sWt[tt][l] = e / sm;                 // nt==0 -> NaN, guarded below
    }
    __syncthreads();

    const float* base = vlog_ws + (size_t)b * (TLEN + 1) * D_MODEL;
    #pragma unroll
    for (int tt = 0; tt < ZT; ++tt) {
        float z = 0.f;
        const int ntc = sN[tt];
        if (ntc > 0) {
            #pragma unroll 8
            for (int m = 0; m < ntc; ++m) {   // wm==0 exactly for m>=ntc
                const float wm = sWt[tt][m];
                z += wm * base[(size_t)sVer[tt][m] * D_MODEL + tid];
            }
        }
        sy[tt][tid] = z;
    }
    __syncthreads();

    float acc[ZT];
    #pragma unroll
    for (int tt = 0; tt < ZT; ++tt) acc[tt] = 0.f;
    for (int i = 0; i < D_MODEL; ++i) {
        const float wo = Wo[i * D_MODEL + tid];
        #pragma unroll
        for (int tt = 0; tt < ZT; ++tt) acc[tt] += sy[tt][i] * wo;
    }
    const float boi = bo[tid];
    #pragma unroll
    for (int tt = 0; tt < ZT; ++tt)
        out[(size_t)(tok0 + tt) * D_MODEL + tid] = acc[tt] + boi;
}

// ---------------------------------------------------------------------------
extern "C" void kernel_launch(void* const* d_in, const int* in_sizes, int n_in,
                              void* d_out, int out_size, void* d_ws, size_t ws_size,
                              hipStream_t stream)
{
    const float* x  = (const float*)d_in[0];
    const float* Wq = (const float*)d_in[1];
    const float* bq = (const float*)d_in[2];
    const float* Wk = (const float*)d_in[3];
    const float* bk = (const float*)d_in[4];
    const float* Wv = (const float*)d_in[5];
    const float* bv = (const float*)d_in[6];
    const float* Wo = (const float*)d_in[7];
    const float* bo = (const float*)d_in[8];
    const float* ls = (const float*)d_in[9];
    float* out = (float*)d_out;

    const int NTOK = BATCH * TLEN;                 // 4096
    char* ws = (char*)d_ws;
    size_t off = 0;
    float* q_ws    = (float*)(ws + off); off += (size_t)NTOK * D_STATE * 4;
    float* k_ws    = (float*)(ws + off); off += (size_t)NTOK * D_STATE * 4;
    float* v_ws    = (float*)(ws + off); off += (size_t)NTOK * D_MODEL * 4;
    float* sims_ws = (float*)(ws + off); off += (size_t)NTOK * MCON * 4;
    int*   ver_ws  = (int*)  (ws + off); off += (size_t)NTOK * MCON * 4;
    int*   n_ws    = (int*)  (ws + off); off += (size_t)NTOK * 4;
    float* vlog_ws = (float*)(ws + off);

    proj_kernel<<<NTOK / PT, 256, 0, stream>>>(x, Wq, bq, Wk, bk, Wv, bv,
                                               q_ws, k_ws, v_ws);
    scan_kernel<<<BATCH, 256, 0, stream>>>(q_ws, k_ws, v_ws,
                                           sims_ws, n_ws, ver_ws, vlog_ws, ls);
    zout_kernel<<<NTOK / ZT, 256, 0, stream>>>(sims_ws, n_ws, ver_ws, vlog_ws,
                                               Wo, bo, out, ls);
}

// Round 13
// 806.188 us; speedup vs baseline: 1.4539x; 1.4539x over previous
//
#include <hip/hip_runtime.h>
#include <hip/hip_bf16.h>

#define D_MODEL 256
#define D_STATE 64
#define MCON    64
#define TLEN    1024
#define BATCH   4
#define NEG_INF -1e9f
#define PT      4      // tokens per proj block (1024 blocks = 4/CU — R25-proven)
#define ZT      4      // tokens per zout block (1024 blocks = 4/CU — R24-proven)

// LDS-ordered workgroup barrier (no vmcnt drain)
#define BAR() asm volatile("s_waitcnt lgkmcnt(0)\n\ts_barrier" ::: "memory")

// ---------------- DPP wave-64 helpers ----------------
template <int CTRL, int RM>
__device__ __forceinline__ float dpp_f(float x) {
    int xi = __float_as_int(x);
    int r  = __builtin_amdgcn_update_dpp(xi, xi, CTRL, RM, 0xf, false);
    return __int_as_float(r);
}
__device__ __forceinline__ float bcast_lane(float x, int lane) {
    return __int_as_float(__builtin_amdgcn_readlane(__float_as_int(x), lane));
}
__device__ __forceinline__ float wave_sum(float x) {
    x += dpp_f<0x111, 0xf>(x);
    x += dpp_f<0x112, 0xf>(x);
    x += dpp_f<0x114, 0xf>(x);
    x += dpp_f<0x118, 0xf>(x);
    x += dpp_f<0x142, 0xa>(x);
    x += dpp_f<0x143, 0xc>(x);
    return bcast_lane(x, 63);
}
__device__ __forceinline__ float wave_max(float x) {
    x = fmaxf(x, dpp_f<0x111, 0xf>(x));
    x = fmaxf(x, dpp_f<0x112, 0xf>(x));
    x = fmaxf(x, dpp_f<0x114, 0xf>(x));
    x = fmaxf(x, dpp_f<0x118, 0xf>(x));
    x = fmaxf(x, dpp_f<0x142, 0xa>(x));
    x = fmaxf(x, dpp_f<0x143, 0xc>(x));
    return bcast_lane(x, 63);
}
// exact argmax with first-index tiebreak (validated R14/R15)
__device__ __forceinline__ int wave_argmax_fast(float lg, float mx) {
    const unsigned long long m = __ballot(lg == mx);
    return (int)(__ffsll((long long)m) - 1);
}
// quad_perm [1,0,3,2]
__device__ __forceinline__ float dpp_swap1(float x) {
    int xi = __float_as_int(x);
    return __int_as_float(__builtin_amdgcn_update_dpp(xi, xi, 0xB1, 0xf, 0xf, false));
}

// ---------------------------------------------------------------------------
// Kernel 1: projections, token-tiled (PT=4 = 1024 blocks, 4/CU). R25-proven.
// ---------------------------------------------------------------------------
__global__ __launch_bounds__(256) void proj_kernel(
    const float* __restrict__ x,
    const float* __restrict__ Wq, const float* __restrict__ bq,
    const float* __restrict__ Wk, const float* __restrict__ bk,
    const float* __restrict__ Wv, const float* __restrict__ bv,
    float* __restrict__ q_ws, float* __restrict__ k_ws, float* __restrict__ v_ws)
{
    const int tok0 = blockIdx.x * PT;
    const int tid  = threadIdx.x;
    __shared__ float sx[PT][D_MODEL];   // 4 KB

    #pragma unroll
    for (int tt = 0; tt < PT; ++tt)
        sx[tt][tid] = x[(size_t)(tok0 + tt) * D_MODEL + tid];
    __syncthreads();

    // v = x @ Wv + bv  (thread tid owns output dim tid; PT tokens at once)
    {
        float acc[PT];
        #pragma unroll
        for (int tt = 0; tt < PT; ++tt) acc[tt] = 0.f;
        for (int i = 0; i < D_MODEL; ++i) {
            const float w = Wv[i * D_MODEL + tid];
            #pragma unroll
            for (int tt = 0; tt < PT; ++tt) acc[tt] += sx[tt][i] * w;
        }
        const float bvi = bv[tid];
        #pragma unroll
        for (int tt = 0; tt < PT; ++tt)
            v_ws[(size_t)(tok0 + tt) * D_MODEL + tid] = acc[tt] + bvi;
    }

    // q (wave 0) / k (wave 1), l2-normalized per token
    if (tid < 128) {
        const int j = tid & 63;
        const float* W  = (tid < 64) ? Wq : Wk;
        const float* bb = (tid < 64) ? bq : bk;
        float a[PT];
        #pragma unroll
        for (int tt = 0; tt < PT; ++tt) a[tt] = 0.f;
        for (int i = 0; i < D_MODEL; ++i) {
            const float w = W[i * D_STATE + j];
            #pragma unroll
            for (int tt = 0; tt < PT; ++tt) a[tt] += sx[tt][i] * w;
        }
        const float bbj = bb[j];
        #pragma unroll
        for (int tt = 0; tt < PT; ++tt) {
            const float av = a[tt] + bbj;
            float s2 = av * av;
            #pragma unroll
            for (int off = 1; off < 64; off <<= 1) s2 += __shfl_xor(s2, off, 64);
            const float nrm = fmaxf(sqrtf(s2), 1e-12f);
            const float o = av / nrm;
            if (tid < 64) q_ws[(size_t)(tok0 + tt) * D_STATE + j] = o;
            else          k_ws[(size_t)(tok0 + tt) * D_STATE + j] = o;
        }
    }
}

// ---------------------------------------------------------------------------
// Kernel 2: scan — R25 champion (688 us): R20 vvt-top-issue + R22 wave-0
// store offload + R25 DPP-max/fupd chain overlap. LDS staging for q/k kept
// (R17/R27 proved the bulk waves' ds_reads are hidden under wave-1's chain;
// replacing them with global loads regressed both times).
// ---------------------------------------------------------------------------
__global__ __launch_bounds__(256) void scan_kernel(
    const float* __restrict__ q_ws, const float* __restrict__ k_ws,
    const float* __restrict__ v_ws,
    float* __restrict__ sims_ws, int* __restrict__ n_ws,
    int* __restrict__ ver_ws, float* __restrict__ vlog_ws,
    const float* __restrict__ ls_p)
{
    const int b   = blockIdx.x;
    const int tid = threadIdx.x;
    const int l   = tid & 63;
    const int wv  = tid >> 6;
    const float scale = fminf(expf(ls_p[0]), 100.f);

    __shared__ __align__(16) float sV[MCON * D_MODEL];   // values (wave1 only)
    __shared__ __align__(16) float sQ[2][D_STATE];
    __shared__ __align__(16) float sK[2][D_STATE];
    __shared__ __align__(16) float sBuf[2][MCON];        // bulkdot (sims_{t+1})
    __shared__ __align__(16) float sS2[2][MCON];         // sum(tmp^2) per row
    __shared__ float sFA[2];                             // f_add = k_t . q_{t+1}
    __shared__ int   sFlagChg[2];
    __shared__ int   sFlagUpd[2];

    const float4 zero4 = make_float4(0.f, 0.f, 0.f, 0.f);
    #pragma unroll
    for (int i = 0; i < 16; ++i) ((float4*)sV)[i * 256 + tid] = zero4;
    if (tid < MCON) { sBuf[0][tid] = 0.f; sS2[0][tid] = 0.f; }
    if (tid == 0) { sFA[0] = 0.f; sFlagChg[0] = -1; sFlagUpd[0] = 0; }

    const float* qg = q_ws + b * TLEN * D_STATE;
    const float* kg = k_ws + b * TLEN * D_STATE;
    const float* vg = v_ws + b * TLEN * D_MODEL;
    float* vlog_b   = vlog_ws + (size_t)b * (TLEN + 1) * D_MODEL;

    if (tid < 64) {
        *(float4*)&vlog_b[4 * l] = zero4;   // vlog slot 0 = zeros
        sQ[1][l] = qg[D_STATE + l];         // q_1
        sK[0][l] = kg[l];                   // k_0
    }

    float qcur = 0.f, kcur = 0.f, qnx2 = 0.f, knx = 0.f;
    float fa_prev = 0.f;                    // wave0: fa posted at t-1 (== sFA[pc])
    int   n0 = 0, ver0 = 0;                 // wave0: replicated bookkeeping
    if (wv == 0) {
        kcur = kg[l];
        qcur = qg[D_STATE + l];
        knx  = kg[D_STATE + l];
        qnx2 = qg[2 * D_STATE + l];
    }
    float  cnt_l = 0.f;
    int    n = 0, chg_prev = -1, upd_prev = 0;
    float4 vvt = zero4;
    if (wv == 1) vvt = *(const float4*)&vg[4 * l];   // v_0
    const int brow = ((wv - 2) << 5) + (l >> 1);
    const int bh   = l & 1;
    float4 Creg[8];
    float4 tprev[8], kprev[8];
    float  s2prev = 0.f;
    #pragma unroll
    for (int c = 0; c < 8; ++c) { Creg[c] = zero4; tprev[c] = zero4; kprev[c] = zero4; }

    __syncthreads();

    for (int t = 0; t < TLEN; ++t) {
        const int token = b * TLEN + t;
        const int pc = t & 1, pn = 1 - pc;

        if (wv >= 2) {
            const int  chg  = sFlagChg[pc];
            const bool updf = sFlagUpd[pc] != 0;
            if (chg == brow) {
                const float rn = 1.f / fmaxf(sqrtf(s2prev), 1e-12f);
                #pragma unroll
                for (int c = 0; c < 8; ++c) {
                    Creg[c].x = updf ? tprev[c].x * rn : kprev[c].x;
                    Creg[c].y = updf ? tprev[c].y * rn : kprev[c].y;
                    Creg[c].z = updf ? tprev[c].z * rn : kprev[c].z;
                    Creg[c].w = updf ? tprev[c].w * rn : kprev[c].w;
                }
            }
            const float* qrow = &sQ[pn][32 * bh];
            const float* krow = &sK[pc][32 * bh];
            float pa = 0.f, pb = 0.f, sa = 0.f, sb = 0.f;
            #pragma unroll
            for (int c = 0; c < 8; ++c) {
                const float4 c4 = Creg[c];
                const float4 q4 = *(const float4*)(qrow + 4 * c);
                const float4 k4 = *(const float4*)(krow + 4 * c);
                float4 t4;
                t4.x = 0.9f * c4.x + 0.1f * k4.x;
                t4.y = 0.9f * c4.y + 0.1f * k4.y;
                t4.z = 0.9f * c4.z + 0.1f * k4.z;
                t4.w = 0.9f * c4.w + 0.1f * k4.w;
                if (c < 4) {
                    pa += c4.x * q4.x; pa += c4.y * q4.y;
                    pa += c4.z * q4.z; pa += c4.w * q4.w;
                    sa += t4.x * t4.x; sa += t4.y * t4.y;
                    sa += t4.z * t4.z; sa += t4.w * t4.w;
                } else {
                    pb += c4.x * q4.x; pb += c4.y * q4.y;
                    pb += c4.z * q4.z; pb += c4.w * q4.w;
                    sb += t4.x * t4.x; sb += t4.y * t4.y;
                    sb += t4.z * t4.z; sb += t4.w * t4.w;
                }
                tprev[c] = t4; kprev[c] = k4;
            }
            const float sd  = pa + pb;
            const float dot = sd + dpp_swap1(sd);
            const float ss  = sa + sb;
            const float s2  = ss + dpp_swap1(ss);
            s2prev = s2;
            if (bh == 0) { sBuf[pn][brow] = dot; sS2[pn][brow] = s2; }
        }

        if (wv == 0) {
            // ---- replicated sims/ver/n bookkeeping + stores (R22) ----
            const int chg0 = sFlagChg[pc];
            const int upd0 = sFlagUpd[pc];
            n0  += (chg0 >= 0 && upd0 == 0) ? 1 : 0;     // do_add at t-1
            if (l == chg0) ver0 = t;                     // ver set at t-1 -> t
            const float bufv0 = sBuf[pc][l];
            const int   ip0   = (chg0 < 0) ? 0 : chg0;
            const float s2v0  = sS2[pc][ip0];
            const float bdc0  = bcast_lane(bufv0, ip0);
            const float fupd0 = (0.9f * bdc0 + 0.1f * fa_prev)
                                / fmaxf(sqrtf(s2v0), 1e-12f);
            const float fsim0 = upd0 ? fupd0 : fa_prev;
            const float simv0 = (l == chg0) ? fsim0 : bufv0;
            sims_ws[(size_t)token * MCON + l] = simv0;
            ver_ws[(size_t)token * MCON + l]  = ver0;
            if (l == 0) n_ws[token] = n0;

            // ---- original wave0 work ----
            sQ[pc][l] = qnx2;
            sK[pn][l] = knx;
            const float fa = wave_sum(kcur * qcur);
            if (l == 0) sFA[pn] = fa;
            fa_prev = fa;
            kcur = knx; qcur = qnx2;
            const int tk2 = (t + 2 < TLEN) ? t + 2 : TLEN - 1;
            const int tq3 = (t + 3 < TLEN) ? t + 3 : TLEN - 1;
            knx  = kg[tk2 * D_STATE + l];
            qnx2 = qg[tq3 * D_STATE + l];
        }

        if (wv == 1) {
            // copy arrived v_t out, then issue v_{t+1} load FIRST (R20)
            const float4 vt = vvt;
            const int tk = (t + 1 < TLEN) ? t + 1 : t;
            vvt = *(const float4*)&vg[tk * D_MODEL + 4 * l];

            const int   ip   = (chg_prev < 0) ? 0 : chg_prev;
            const float bufv = sBuf[pc][l];

            // R25: DPP max over bufv lanes (chg_prev masked out) runs in
            // parallel with the fupd chain; fmax is associative -> bit-exact.
            const float lgO = ((l < n && l != chg_prev) ? bufv : NEG_INF) * scale;
            const float mxO = wave_max(lgO);

            const float s2v  = sS2[pc][ip];
            const float fa   = sFA[pc];
            const float bdc  = bcast_lane(bufv, ip);
            const float fupd = (0.9f * bdc + 0.1f * fa)
                               / fmaxf(sqrtf(s2v), 1e-12f);
            const float fsim = upd_prev ? fupd : fa;          // wave-uniform
            const float simv = (l == chg_prev) ? fsim : bufv;

            const float lgC = ((chg_prev >= 0) ? fsim : NEG_INF) * scale;
            const float mx  = fmaxf(mxO, lgC);
            const float lg  = ((l < n) ? simv : NEG_INF) * scale;
            const int   sel    = wave_argmax_fast(lg, mx);
            const float selSim = bcast_lane(simv,  sel);
            const float cnt    = bcast_lane(cnt_l, sel);

            const float4 vs = *(const float4*)&sV[sel * D_MODEL + 4 * l];
            float r = (vs.x - vt.x) * (vs.x - vt.x)
                    + (vs.y - vt.y) * (vs.y - vt.y)
                    + (vs.z - vt.z) * (vs.z - vt.z)
                    + (vs.w - vt.w) * (vs.w - vt.w);
            const float residual = sqrtf(wave_sum(r) * (1.f / 256.f));

            const bool has = n > 0;
            const bool refine = has && (n < MCON) &&
                                (selSim < 0.75f || residual > 1.0f);
            const bool do_add    = ((!has) || refine) && (n < MCON);
            const bool do_update = has && !refine;
            const int  chg = do_update ? sel : n;

            float4 nv;
            nv.x = (vs.x * cnt + vt.x) / (cnt + 1.f);
            nv.y = (vs.y * cnt + vt.y) / (cnt + 1.f);
            nv.z = (vs.z * cnt + vt.z) / (cnt + 1.f);
            nv.w = (vs.w * cnt + vt.w) / (cnt + 1.f);
            float4 valV;
            valV.x = do_update ? nv.x : vt.x;
            valV.y = do_update ? nv.y : vt.y;
            valV.z = do_update ? nv.z : vt.z;
            valV.w = do_update ? nv.w : vt.w;
            *(float4*)&sV[chg * D_MODEL + 4 * l] = valV;
            *(float4*)&vlog_b[(size_t)(t + 1) * D_MODEL + 4 * l] = valV;

            if (l == 0) { sFlagChg[pn] = chg; sFlagUpd[pn] = do_update ? 1 : 0; }

            if (l == sel && do_update) cnt_l = cnt + 1.f;
            if (l == n   && do_add)    cnt_l = 1.f;
            n += do_add ? 1 : 0;
            chg_prev = chg; upd_prev = do_update ? 1 : 0;
        }

        BAR();
    }
}

// ---------------------------------------------------------------------------
// Kernel 3: fused payload, token-tiled (ZT=4 = 1024 blocks, 4/CU). R25-proven.
// ---------------------------------------------------------------------------
__global__ __launch_bounds__(256) void zout_kernel(
    const float* __restrict__ sims_ws, const int* __restrict__ n_ws,
    const int* __restrict__ ver_ws, const float* __restrict__ vlog_ws,
    const float* __restrict__ Wo, const float* __restrict__ bo,
    float* __restrict__ out, const float* __restrict__ ls_p)
{
    const int tok0 = blockIdx.x * ZT;
    const int b    = tok0 >> 10;             // ZT divides TLEN -> same seq
    const int tid  = threadIdx.x;
    const int l    = tid & 63;
    const int wv   = tid >> 6;
    const float scale = fminf(expf(ls_p[0]), 100.f);

    __shared__ float sWt[ZT][MCON];
    __shared__ int   sVer[ZT][MCON];
    __shared__ int   sN[ZT];
    __shared__ float sy[ZT][D_MODEL];

    // softmax + ver loads: wave wv handles token tt = wv (ZT==4)
    for (int tt = wv; tt < ZT; tt += 4) {
        const int token = tok0 + tt;
        const int nt = n_ws[token];
        if (l == 0) sN[tt] = nt;
        sVer[tt][l] = ver_ws[(size_t)token * MCON + l];
        const float simv = sims_ws[(size_t)token * MCON + l];
        const float lg = ((l < nt) ? simv : NEG_INF) * scale;
        const float mx = wave_max(lg);
        const float e  = expf(lg - mx);
        const float sm = wave_sum(e);
        sWt[tt][l] = e / sm;                 // nt==0 -> NaN, guarded below
    }
    __syncthreads();

    const float* base = vlog_ws + (size_t)b * (TLEN + 1) * D_MODEL;
    #pragma unroll
    for (int tt = 0; tt < ZT; ++tt) {
        float z = 0.f;
        const int ntc = sN[tt];
        if (ntc > 0) {
            #pragma unroll 8
            for (int m = 0; m < ntc; ++m) {   // wm==0 exactly for m>=ntc
                const float wm = sWt[tt][m];
                z += wm * base[(size_t)sVer[tt][m] * D_MODEL + tid];
            }
        }
        sy[tt][tid] = z;
    }
    __syncthreads();

    float acc[ZT];
    #pragma unroll
    for (int tt = 0; tt < ZT; ++tt) acc[tt] = 0.f;
    for (int i = 0; i < D_MODEL; ++i) {
        const float wo = Wo[i * D_MODEL + tid];
        #pragma unroll
        for (int tt = 0; tt < ZT; ++tt) acc[tt] += sy[tt][i] * wo;
    }
    const float boi = bo[tid];
    #pragma unroll
    for (int tt = 0; tt < ZT; ++tt)
        out[(size_t)(tok0 + tt) * D_MODEL + tid] = acc[tt] + boi;
}

// ---------------------------------------------------------------------------
extern "C" void kernel_launch(void* const* d_in, const int* in_sizes, int n_in,
                              void* d_out, int out_size, void* d_ws, size_t ws_size,
                              hipStream_t stream)
{
    const float* x  = (const float*)d_in[0];
    const float* Wq = (const float*)d_in[1];
    const float* bq = (const float*)d_in[2];
    const float* Wk = (const float*)d_in[3];
    const float* bk = (const float*)d_in[4];
    const float* Wv = (const float*)d_in[5];
    const float* bv = (const float*)d_in[6];
    const float* Wo = (const float*)d_in[7];
    const float* bo = (const float*)d_in[8];
    const float* ls = (const float*)d_in[9];
    float* out = (float*)d_out;

    const int NTOK = BATCH * TLEN;                 // 4096
    char* ws = (char*)d_ws;
    size_t off = 0;
    float* q_ws    = (float*)(ws + off); off += (size_t)NTOK * D_STATE * 4;
    float* k_ws    = (float*)(ws + off); off += (size_t)NTOK * D_STATE * 4;
    float* v_ws    = (float*)(ws + off); off += (size_t)NTOK * D_MODEL * 4;
    float* sims_ws = (float*)(ws + off); off += (size_t)NTOK * MCON * 4;
    int*   ver_ws  = (int*)  (ws + off); off += (size_t)NTOK * MCON * 4;
    int*   n_ws    = (int*)  (ws + off); off += (size_t)NTOK * 4;
    float* vlog_ws = (float*)(ws + off);

    proj_kernel<<<NTOK / PT, 256, 0, stream>>>(x, Wq, bq, Wk, bk, Wv, bv,
                                               q_ws, k_ws, v_ws);
    scan_kernel<<<BATCH, 256, 0, stream>>>(q_ws, k_ws, v_ws,
                                           sims_ws, n_ws, ver_ws, vlog_ws, ls);
    zout_kernel<<<NTOK / ZT, 256, 0, stream>>>(sims_ws, n_ws, ver_ws, vlog_ws,
                                               Wo, bo, out, ls);
}

// Round 14
// 800.926 us; speedup vs baseline: 1.4634x; 1.0066x over previous
//
#include <hip/hip_runtime.h>
#include <hip/hip_bf16.h>

#define D_MODEL 256
#define D_STATE 64
#define MCON    64
#define TLEN    1024
#define BATCH   4
#define NEG_INF -1e9f
#define PT      4      // tokens per proj block (1024 blocks = 4/CU — R25-proven)
#define ZT      4      // tokens per zout block (1024 blocks = 4/CU — R24-proven)

// LDS-ordered workgroup barrier (no vmcnt drain)
#define BAR() asm volatile("s_waitcnt lgkmcnt(0)\n\ts_barrier" ::: "memory")

// ---------------- DPP wave-64 helpers ----------------
template <int CTRL, int RM>
__device__ __forceinline__ float dpp_f(float x) {
    int xi = __float_as_int(x);
    int r  = __builtin_amdgcn_update_dpp(xi, xi, CTRL, RM, 0xf, false);
    return __int_as_float(r);
}
__device__ __forceinline__ float bcast_lane(float x, int lane) {
    return __int_as_float(__builtin_amdgcn_readlane(__float_as_int(x), lane));
}
__device__ __forceinline__ float wave_sum(float x) {
    x += dpp_f<0x111, 0xf>(x);
    x += dpp_f<0x112, 0xf>(x);
    x += dpp_f<0x114, 0xf>(x);
    x += dpp_f<0x118, 0xf>(x);
    x += dpp_f<0x142, 0xa>(x);
    x += dpp_f<0x143, 0xc>(x);
    return bcast_lane(x, 63);
}
__device__ __forceinline__ float wave_max(float x) {
    x = fmaxf(x, dpp_f<0x111, 0xf>(x));
    x = fmaxf(x, dpp_f<0x112, 0xf>(x));
    x = fmaxf(x, dpp_f<0x114, 0xf>(x));
    x = fmaxf(x, dpp_f<0x118, 0xf>(x));
    x = fmaxf(x, dpp_f<0x142, 0xa>(x));
    x = fmaxf(x, dpp_f<0x143, 0xc>(x));
    return bcast_lane(x, 63);
}
// exact argmax with first-index tiebreak (validated R14/R15)
__device__ __forceinline__ int wave_argmax_fast(float lg, float mx) {
    const unsigned long long m = __ballot(lg == mx);
    return (int)(__ffsll((long long)m) - 1);
}
// quad_perm [1,0,3,2]
__device__ __forceinline__ float dpp_swap1(float x) {
    int xi = __float_as_int(x);
    return __int_as_float(__builtin_amdgcn_update_dpp(xi, xi, 0xB1, 0xf, 0xf, false));
}

// ---------------------------------------------------------------------------
// Kernel 1: projections, token-tiled (PT=4 = 1024 blocks, 4/CU). R25-proven.
// ---------------------------------------------------------------------------
__global__ __launch_bounds__(256) void proj_kernel(
    const float* __restrict__ x,
    const float* __restrict__ Wq, const float* __restrict__ bq,
    const float* __restrict__ Wk, const float* __restrict__ bk,
    const float* __restrict__ Wv, const float* __restrict__ bv,
    float* __restrict__ q_ws, float* __restrict__ k_ws, float* __restrict__ v_ws)
{
    const int tok0 = blockIdx.x * PT;
    const int tid  = threadIdx.x;
    __shared__ float sx[PT][D_MODEL];   // 4 KB

    #pragma unroll
    for (int tt = 0; tt < PT; ++tt)
        sx[tt][tid] = x[(size_t)(tok0 + tt) * D_MODEL + tid];
    __syncthreads();

    // v = x @ Wv + bv  (thread tid owns output dim tid; PT tokens at once)
    {
        float acc[PT];
        #pragma unroll
        for (int tt = 0; tt < PT; ++tt) acc[tt] = 0.f;
        for (int i = 0; i < D_MODEL; ++i) {
            const float w = Wv[i * D_MODEL + tid];
            #pragma unroll
            for (int tt = 0; tt < PT; ++tt) acc[tt] += sx[tt][i] * w;
        }
        const float bvi = bv[tid];
        #pragma unroll
        for (int tt = 0; tt < PT; ++tt)
            v_ws[(size_t)(tok0 + tt) * D_MODEL + tid] = acc[tt] + bvi;
    }

    // q (wave 0) / k (wave 1), l2-normalized per token
    if (tid < 128) {
        const int j = tid & 63;
        const float* W  = (tid < 64) ? Wq : Wk;
        const float* bb = (tid < 64) ? bq : bk;
        float a[PT];
        #pragma unroll
        for (int tt = 0; tt < PT; ++tt) a[tt] = 0.f;
        for (int i = 0; i < D_MODEL; ++i) {
            const float w = W[i * D_STATE + j];
            #pragma unroll
            for (int tt = 0; tt < PT; ++tt) a[tt] += sx[tt][i] * w;
        }
        const float bbj = bb[j];
        #pragma unroll
        for (int tt = 0; tt < PT; ++tt) {
            const float av = a[tt] + bbj;
            float s2 = av * av;
            #pragma unroll
            for (int off = 1; off < 64; off <<= 1) s2 += __shfl_xor(s2, off, 64);
            const float nrm = fmaxf(sqrtf(s2), 1e-12f);
            const float o = av / nrm;
            if (tid < 64) q_ws[(size_t)(tok0 + tt) * D_STATE + j] = o;
            else          k_ws[(size_t)(tok0 + tt) * D_STATE + j] = o;
        }
    }
}

// ---------------------------------------------------------------------------
// Kernel 2: scan — R25 champion body. R29 change: wave 1 (the critical
// serial chain) runs at s_setprio(1); other waves stay at priority 0.
// Pure scheduling hint — zero numerical effect; all values byte-identical.
// ---------------------------------------------------------------------------
__global__ __launch_bounds__(256) void scan_kernel(
    const float* __restrict__ q_ws, const float* __restrict__ k_ws,
    const float* __restrict__ v_ws,
    float* __restrict__ sims_ws, int* __restrict__ n_ws,
    int* __restrict__ ver_ws, float* __restrict__ vlog_ws,
    const float* __restrict__ ls_p)
{
    const int b   = blockIdx.x;
    const int tid = threadIdx.x;
    const int l   = tid & 63;
    const int wv  = tid >> 6;
    const float scale = fminf(expf(ls_p[0]), 100.f);

    __shared__ __align__(16) float sV[MCON * D_MODEL];   // values (wave1 only)
    __shared__ __align__(16) float sQ[2][D_STATE];
    __shared__ __align__(16) float sK[2][D_STATE];
    __shared__ __align__(16) float sBuf[2][MCON];        // bulkdot (sims_{t+1})
    __shared__ __align__(16) float sS2[2][MCON];         // sum(tmp^2) per row
    __shared__ float sFA[2];                             // f_add = k_t . q_{t+1}
    __shared__ int   sFlagChg[2];
    __shared__ int   sFlagUpd[2];

    const float4 zero4 = make_float4(0.f, 0.f, 0.f, 0.f);
    #pragma unroll
    for (int i = 0; i < 16; ++i) ((float4*)sV)[i * 256 + tid] = zero4;
    if (tid < MCON) { sBuf[0][tid] = 0.f; sS2[0][tid] = 0.f; }
    if (tid == 0) { sFA[0] = 0.f; sFlagChg[0] = -1; sFlagUpd[0] = 0; }

    const float* qg = q_ws + b * TLEN * D_STATE;
    const float* kg = k_ws + b * TLEN * D_STATE;
    const float* vg = v_ws + b * TLEN * D_MODEL;
    float* vlog_b   = vlog_ws + (size_t)b * (TLEN + 1) * D_MODEL;

    if (tid < 64) {
        *(float4*)&vlog_b[4 * l] = zero4;   // vlog slot 0 = zeros
        sQ[1][l] = qg[D_STATE + l];         // q_1
        sK[0][l] = kg[l];                   // k_0
    }

    float qcur = 0.f, kcur = 0.f, qnx2 = 0.f, knx = 0.f;
    float fa_prev = 0.f;                    // wave0: fa posted at t-1 (== sFA[pc])
    int   n0 = 0, ver0 = 0;                 // wave0: replicated bookkeeping
    if (wv == 0) {
        kcur = kg[l];
        qcur = qg[D_STATE + l];
        knx  = kg[D_STATE + l];
        qnx2 = qg[2 * D_STATE + l];
    }
    float  cnt_l = 0.f;
    int    n = 0, chg_prev = -1, upd_prev = 0;
    float4 vvt = zero4;
    if (wv == 1) vvt = *(const float4*)&vg[4 * l];   // v_0
    const int brow = ((wv - 2) << 5) + (l >> 1);
    const int bh   = l & 1;
    float4 Creg[8];
    float4 tprev[8], kprev[8];
    float  s2prev = 0.f;
    #pragma unroll
    for (int c = 0; c < 8; ++c) { Creg[c] = zero4; tprev[c] = zero4; kprev[c] = zero4; }

    __syncthreads();

    // R29: boost the critical wave's issue priority for the whole scan.
    if (wv == 1) __builtin_amdgcn_s_setprio(1);

    for (int t = 0; t < TLEN; ++t) {
        const int token = b * TLEN + t;
        const int pc = t & 1, pn = 1 - pc;

        if (wv >= 2) {
            const int  chg  = sFlagChg[pc];
            const bool updf = sFlagUpd[pc] != 0;
            if (chg == brow) {
                const float rn = 1.f / fmaxf(sqrtf(s2prev), 1e-12f);
                #pragma unroll
                for (int c = 0; c < 8; ++c) {
                    Creg[c].x = updf ? tprev[c].x * rn : kprev[c].x;
                    Creg[c].y = updf ? tprev[c].y * rn : kprev[c].y;
                    Creg[c].z = updf ? tprev[c].z * rn : kprev[c].z;
                    Creg[c].w = updf ? tprev[c].w * rn : kprev[c].w;
                }
            }
            const float* qrow = &sQ[pn][32 * bh];
            const float* krow = &sK[pc][32 * bh];
            float pa = 0.f, pb = 0.f, sa = 0.f, sb = 0.f;
            #pragma unroll
            for (int c = 0; c < 8; ++c) {
                const float4 c4 = Creg[c];
                const float4 q4 = *(const float4*)(qrow + 4 * c);
                const float4 k4 = *(const float4*)(krow + 4 * c);
                float4 t4;
                t4.x = 0.9f * c4.x + 0.1f * k4.x;
                t4.y = 0.9f * c4.y + 0.1f * k4.y;
                t4.z = 0.9f * c4.z + 0.1f * k4.z;
                t4.w = 0.9f * c4.w + 0.1f * k4.w;
                if (c < 4) {
                    pa += c4.x * q4.x; pa += c4.y * q4.y;
                    pa += c4.z * q4.z; pa += c4.w * q4.w;
                    sa += t4.x * t4.x; sa += t4.y * t4.y;
                    sa += t4.z * t4.z; sa += t4.w * t4.w;
                } else {
                    pb += c4.x * q4.x; pb += c4.y * q4.y;
                    pb += c4.z * q4.z; pb += c4.w * q4.w;
                    sb += t4.x * t4.x; sb += t4.y * t4.y;
                    sb += t4.z * t4.z; sb += t4.w * t4.w;
                }
                tprev[c] = t4; kprev[c] = k4;
            }
            const float sd  = pa + pb;
            const float dot = sd + dpp_swap1(sd);
            const float ss  = sa + sb;
            const float s2  = ss + dpp_swap1(ss);
            s2prev = s2;
            if (bh == 0) { sBuf[pn][brow] = dot; sS2[pn][brow] = s2; }
        }

        if (wv == 0) {
            // ---- replicated sims/ver/n bookkeeping + stores (R22) ----
            const int chg0 = sFlagChg[pc];
            const int upd0 = sFlagUpd[pc];
            n0  += (chg0 >= 0 && upd0 == 0) ? 1 : 0;     // do_add at t-1
            if (l == chg0) ver0 = t;                     // ver set at t-1 -> t
            const float bufv0 = sBuf[pc][l];
            const int   ip0   = (chg0 < 0) ? 0 : chg0;
            const float s2v0  = sS2[pc][ip0];
            const float bdc0  = bcast_lane(bufv0, ip0);
            const float fupd0 = (0.9f * bdc0 + 0.1f * fa_prev)
                                / fmaxf(sqrtf(s2v0), 1e-12f);
            const float fsim0 = upd0 ? fupd0 : fa_prev;
            const float simv0 = (l == chg0) ? fsim0 : bufv0;
            sims_ws[(size_t)token * MCON + l] = simv0;
            ver_ws[(size_t)token * MCON + l]  = ver0;
            if (l == 0) n_ws[token] = n0;

            // ---- original wave0 work ----
            sQ[pc][l] = qnx2;
            sK[pn][l] = knx;
            const float fa = wave_sum(kcur * qcur);
            if (l == 0) sFA[pn] = fa;
            fa_prev = fa;
            kcur = knx; qcur = qnx2;
            const int tk2 = (t + 2 < TLEN) ? t + 2 : TLEN - 1;
            const int tq3 = (t + 3 < TLEN) ? t + 3 : TLEN - 1;
            knx  = kg[tk2 * D_STATE + l];
            qnx2 = qg[tq3 * D_STATE + l];
        }

        if (wv == 1) {
            // copy arrived v_t out, then issue v_{t+1} load FIRST (R20)
            const float4 vt = vvt;
            const int tk = (t + 1 < TLEN) ? t + 1 : t;
            vvt = *(const float4*)&vg[tk * D_MODEL + 4 * l];

            const int   ip   = (chg_prev < 0) ? 0 : chg_prev;
            const float bufv = sBuf[pc][l];

            // R25: DPP max over bufv lanes (chg_prev masked out) runs in
            // parallel with the fupd chain; fmax is associative -> bit-exact.
            const float lgO = ((l < n && l != chg_prev) ? bufv : NEG_INF) * scale;
            const float mxO = wave_max(lgO);

            const float s2v  = sS2[pc][ip];
            const float fa   = sFA[pc];
            const float bdc  = bcast_lane(bufv, ip);
            const float fupd = (0.9f * bdc + 0.1f * fa)
                               / fmaxf(sqrtf(s2v), 1e-12f);
            const float fsim = upd_prev ? fupd : fa;          // wave-uniform
            const float simv = (l == chg_prev) ? fsim : bufv;

            const float lgC = ((chg_prev >= 0) ? fsim : NEG_INF) * scale;
            const float mx  = fmaxf(mxO, lgC);
            const float lg  = ((l < n) ? simv : NEG_INF) * scale;
            const int   sel    = wave_argmax_fast(lg, mx);
            const float selSim = bcast_lane(simv,  sel);
            const float cnt    = bcast_lane(cnt_l, sel);

            const float4 vs = *(const float4*)&sV[sel * D_MODEL + 4 * l];
            float r = (vs.x - vt.x) * (vs.x - vt.x)
                    + (vs.y - vt.y) * (vs.y - vt.y)
                    + (vs.z - vt.z) * (vs.z - vt.z)
                    + (vs.w - vt.w) * (vs.w - vt.w);
            const float residual = sqrtf(wave_sum(r) * (1.f / 256.f));

            const bool has = n > 0;
            const bool refine = has && (n < MCON) &&
                                (selSim < 0.75f || residual > 1.0f);
            const bool do_add    = ((!has) || refine) && (n < MCON);
            const bool do_update = has && !refine;
            const int  chg = do_update ? sel : n;

            float4 nv;
            nv.x = (vs.x * cnt + vt.x) / (cnt + 1.f);
            nv.y = (vs.y * cnt + vt.y) / (cnt + 1.f);
            nv.z = (vs.z * cnt + vt.z) / (cnt + 1.f);
            nv.w = (vs.w * cnt + vt.w) / (cnt + 1.f);
            float4 valV;
            valV.x = do_update ? nv.x : vt.x;
            valV.y = do_update ? nv.y : vt.y;
            valV.z = do_update ? nv.z : vt.z;
            valV.w = do_update ? nv.w : vt.w;
            *(float4*)&sV[chg * D_MODEL + 4 * l] = valV;
            *(float4*)&vlog_b[(size_t)(t + 1) * D_MODEL + 4 * l] = valV;

            if (l == 0) { sFlagChg[pn] = chg; sFlagUpd[pn] = do_update ? 1 : 0; }

            if (l == sel && do_update) cnt_l = cnt + 1.f;
            if (l == n   && do_add)    cnt_l = 1.f;
            n += do_add ? 1 : 0;
            chg_prev = chg; upd_prev = do_update ? 1 : 0;
        }

        BAR();
    }
}

// ---------------------------------------------------------------------------
// Kernel 3: fused payload, token-tiled (ZT=4 = 1024 blocks, 4/CU). R25-proven.
// ---------------------------------------------------------------------------
__global__ __launch_bounds__(256) void zout_kernel(
    const float* __restrict__ sims_ws, const int* __restrict__ n_ws,
    const int* __restrict__ ver_ws, const float* __restrict__ vlog_ws,
    const float* __restrict__ Wo, const float* __restrict__ bo,
    float* __restrict__ out, const float* __restrict__ ls_p)
{
    const int tok0 = blockIdx.x * ZT;
    const int b    = tok0 >> 10;             // ZT divides TLEN -> same seq
    const int tid  = threadIdx.x;
    const int l    = tid & 63;
    const int wv   = tid >> 6;
    const float scale = fminf(expf(ls_p[0]), 100.f);

    __shared__ float sWt[ZT][MCON];
    __shared__ int   sVer[ZT][MCON];
    __shared__ int   sN[ZT];
    __shared__ float sy[ZT][D_MODEL];

    // softmax + ver loads: wave wv handles token tt = wv (ZT==4)
    for (int tt = wv; tt < ZT; tt += 4) {
        const int token = tok0 + tt;
        const int nt = n_ws[token];
        if (l == 0) sN[tt] = nt;
        sVer[tt][l] = ver_ws[(size_t)token * MCON + l];
        const float simv = sims_ws[(size_t)token * MCON + l];
        const float lg = ((l < nt) ? simv : NEG_INF) * scale;
        const float mx = wave_max(lg);
        const float e  = expf(lg - mx);
        const float sm = wave_sum(e);
        sWt[tt][l] = e / sm;                 // nt==0 -> NaN, guarded below
    }
    __syncthreads();

    const float* base = vlog_ws + (size_t)b * (TLEN + 1) * D_MODEL;
    #pragma unroll
    for (int tt = 0; tt < ZT; ++tt) {
        float z = 0.f;
        const int ntc = sN[tt];
        if (ntc > 0) {
            #pragma unroll 8
            for (int m = 0; m < ntc; ++m) {   // wm==0 exactly for m>=ntc
                const float wm = sWt[tt][m];
                z += wm * base[(size_t)sVer[tt][m] * D_MODEL + tid];
            }
        }
        sy[tt][tid] = z;
    }
    __syncthreads();

    float acc[ZT];
    #pragma unroll
    for (int tt = 0; tt < ZT; ++tt) acc[tt] = 0.f;
    for (int i = 0; i < D_MODEL; ++i) {
        const float wo = Wo[i * D_MODEL + tid];
        #pragma unroll
        for (int tt = 0; tt < ZT; ++tt) acc[tt] += sy[tt][i] * wo;
    }
    const float boi = bo[tid];
    #pragma unroll
    for (int tt = 0; tt < ZT; ++tt)
        out[(size_t)(tok0 + tt) * D_MODEL + tid] = acc[tt] + boi;
}

// ---------------------------------------------------------------------------
extern "C" void kernel_launch(void* const* d_in, const int* in_sizes, int n_in,
                              void* d_out, int out_size, void* d_ws, size_t ws_size,
                              hipStream_t stream)
{
    const float* x  = (const float*)d_in[0];
    const float* Wq = (const float*)d_in[1];
    const float* bq = (const float*)d_in[2];
    const float* Wk = (const float*)d_in[3];
    const float* bk = (const float*)d_in[4];
    const float* Wv = (const float*)d_in[5];
    const float* bv = (const float*)d_in[6];
    const float* Wo = (const float*)d_in[7];
    const float* bo = (const float*)d_in[8];
    const float* ls = (const float*)d_in[9];
    float* out = (float*)d_out;

    const int NTOK = BATCH * TLEN;                 // 4096
    char* ws = (char*)d_ws;
    size_t off = 0;
    float* q_ws    = (float*)(ws + off); off += (size_t)NTOK * D_STATE * 4;
    float* k_ws    = (float*)(ws + off); off += (size_t)NTOK * D_STATE * 4;
    float* v_ws    = (float*)(ws + off); off += (size_t)NTOK * D_MODEL * 4;
    float* sims_ws = (float*)(ws + off); off += (size_t)NTOK * MCON * 4;
    int*   ver_ws  = (int*)  (ws + off); off += (size_t)NTOK * MCON * 4;
    int*   n_ws    = (int*)  (ws + off); off += (size_t)NTOK * 4;
    float* vlog_ws = (float*)(ws + off);

    proj_kernel<<<NTOK / PT, 256, 0, stream>>>(x, Wq, bq, Wk, bk, Wv, bv,
                                               q_ws, k_ws, v_ws);
    scan_kernel<<<BATCH, 256, 0, stream>>>(q_ws, k_ws, v_ws,
                                           sims_ws, n_ws, ver_ws, vlog_ws, ls);
    zout_kernel<<<NTOK / ZT, 256, 0, stream>>>(sims_ws, n_ws, ver_ws, vlog_ws,
                                               Wo, bo, out, ls);
}

// Round 15
// 794.974 us; speedup vs baseline: 1.4744x; 1.0075x over previous
//
#include <hip/hip_runtime.h>
#include <hip/hip_bf16.h>

#define D_MODEL 256
#define D_STATE 64
#define MCON    64
#define TLEN    1024
#define BATCH   4
#define NEG_INF -1e9f
#define PT      4      // tokens per proj block (1024 blocks = 4/CU — R25-proven)
#define ZT      4      // tokens per zout block (1024 blocks = 4/CU — R24-proven)

// LDS-ordered workgroup barrier (no vmcnt drain)
#define BAR() asm volatile("s_waitcnt lgkmcnt(0)\n\ts_barrier" ::: "memory")

// ---------------- DPP wave-64 helpers ----------------
template <int CTRL, int RM>
__device__ __forceinline__ float dpp_f(float x) {
    int xi = __float_as_int(x);
    int r  = __builtin_amdgcn_update_dpp(xi, xi, CTRL, RM, 0xf, false);
    return __int_as_float(r);
}
__device__ __forceinline__ float bcast_lane(float x, int lane) {
    return __int_as_float(__builtin_amdgcn_readlane(__float_as_int(x), lane));
}
__device__ __forceinline__ float wave_sum(float x) {
    x += dpp_f<0x111, 0xf>(x);
    x += dpp_f<0x112, 0xf>(x);
    x += dpp_f<0x114, 0xf>(x);
    x += dpp_f<0x118, 0xf>(x);
    x += dpp_f<0x142, 0xa>(x);
    x += dpp_f<0x143, 0xc>(x);
    return bcast_lane(x, 63);
}
__device__ __forceinline__ float wave_max(float x) {
    x = fmaxf(x, dpp_f<0x111, 0xf>(x));
    x = fmaxf(x, dpp_f<0x112, 0xf>(x));
    x = fmaxf(x, dpp_f<0x114, 0xf>(x));
    x = fmaxf(x, dpp_f<0x118, 0xf>(x));
    x = fmaxf(x, dpp_f<0x142, 0xa>(x));
    x = fmaxf(x, dpp_f<0x143, 0xc>(x));
    return bcast_lane(x, 63);
}
// exact argmax with first-index tiebreak (validated R14/R15)
__device__ __forceinline__ int wave_argmax_fast(float lg, float mx) {
    const unsigned long long m = __ballot(lg == mx);
    return (int)(__ffsll((long long)m) - 1);
}
// quad_perm [1,0,3,2]
__device__ __forceinline__ float dpp_swap1(float x) {
    int xi = __float_as_int(x);
    return __int_as_float(__builtin_amdgcn_update_dpp(xi, xi, 0xB1, 0xf, 0xf, false));
}

// ---------------------------------------------------------------------------
// Kernel 1: projections, token-tiled (PT=4 = 1024 blocks, 4/CU). R25-proven.
// ---------------------------------------------------------------------------
__global__ __launch_bounds__(256) void proj_kernel(
    const float* __restrict__ x,
    const float* __restrict__ Wq, const float* __restrict__ bq,
    const float* __restrict__ Wk, const float* __restrict__ bk,
    const float* __restrict__ Wv, const float* __restrict__ bv,
    float* __restrict__ q_ws, float* __restrict__ k_ws, float* __restrict__ v_ws)
{
    const int tok0 = blockIdx.x * PT;
    const int tid  = threadIdx.x;
    __shared__ float sx[PT][D_MODEL];   // 4 KB

    #pragma unroll
    for (int tt = 0; tt < PT; ++tt)
        sx[tt][tid] = x[(size_t)(tok0 + tt) * D_MODEL + tid];
    __syncthreads();

    // v = x @ Wv + bv  (thread tid owns output dim tid; PT tokens at once)
    {
        float acc[PT];
        #pragma unroll
        for (int tt = 0; tt < PT; ++tt) acc[tt] = 0.f;
        for (int i = 0; i < D_MODEL; ++i) {
            const float w = Wv[i * D_MODEL + tid];
            #pragma unroll
            for (int tt = 0; tt < PT; ++tt) acc[tt] += sx[tt][i] * w;
        }
        const float bvi = bv[tid];
        #pragma unroll
        for (int tt = 0; tt < PT; ++tt)
            v_ws[(size_t)(tok0 + tt) * D_MODEL + tid] = acc[tt] + bvi;
    }

    // q (wave 0) / k (wave 1), l2-normalized per token
    if (tid < 128) {
        const int j = tid & 63;
        const float* W  = (tid < 64) ? Wq : Wk;
        const float* bb = (tid < 64) ? bq : bk;
        float a[PT];
        #pragma unroll
        for (int tt = 0; tt < PT; ++tt) a[tt] = 0.f;
        for (int i = 0; i < D_MODEL; ++i) {
            const float w = W[i * D_STATE + j];
            #pragma unroll
            for (int tt = 0; tt < PT; ++tt) a[tt] += sx[tt][i] * w;
        }
        const float bbj = bb[j];
        #pragma unroll
        for (int tt = 0; tt < PT; ++tt) {
            const float av = a[tt] + bbj;
            float s2 = av * av;
            #pragma unroll
            for (int off = 1; off < 64; off <<= 1) s2 += __shfl_xor(s2, off, 64);
            const float nrm = fmaxf(sqrtf(s2), 1e-12f);
            const float o = av / nrm;
            if (tid < 64) q_ws[(size_t)(tok0 + tt) * D_STATE + j] = o;
            else          k_ws[(size_t)(tok0 + tt) * D_STATE + j] = o;
        }
    }
}

// ---------------------------------------------------------------------------
// Kernel 2: scan — R29 champion body (675 us). R30 change: full priority
// ordering matching criticality — wave 1 (critical chain) prio 2, wave 0
// (secondary: fa + replicated stores) prio 1, bulk waves prio 0.
// Pure scheduling hint — zero numerical effect; values byte-identical.
// ---------------------------------------------------------------------------
__global__ __launch_bounds__(256) void scan_kernel(
    const float* __restrict__ q_ws, const float* __restrict__ k_ws,
    const float* __restrict__ v_ws,
    float* __restrict__ sims_ws, int* __restrict__ n_ws,
    int* __restrict__ ver_ws, float* __restrict__ vlog_ws,
    const float* __restrict__ ls_p)
{
    const int b   = blockIdx.x;
    const int tid = threadIdx.x;
    const int l   = tid & 63;
    const int wv  = tid >> 6;
    const float scale = fminf(expf(ls_p[0]), 100.f);

    __shared__ __align__(16) float sV[MCON * D_MODEL];   // values (wave1 only)
    __shared__ __align__(16) float sQ[2][D_STATE];
    __shared__ __align__(16) float sK[2][D_STATE];
    __shared__ __align__(16) float sBuf[2][MCON];        // bulkdot (sims_{t+1})
    __shared__ __align__(16) float sS2[2][MCON];         // sum(tmp^2) per row
    __shared__ float sFA[2];                             // f_add = k_t . q_{t+1}
    __shared__ int   sFlagChg[2];
    __shared__ int   sFlagUpd[2];

    const float4 zero4 = make_float4(0.f, 0.f, 0.f, 0.f);
    #pragma unroll
    for (int i = 0; i < 16; ++i) ((float4*)sV)[i * 256 + tid] = zero4;
    if (tid < MCON) { sBuf[0][tid] = 0.f; sS2[0][tid] = 0.f; }
    if (tid == 0) { sFA[0] = 0.f; sFlagChg[0] = -1; sFlagUpd[0] = 0; }

    const float* qg = q_ws + b * TLEN * D_STATE;
    const float* kg = k_ws + b * TLEN * D_STATE;
    const float* vg = v_ws + b * TLEN * D_MODEL;
    float* vlog_b   = vlog_ws + (size_t)b * (TLEN + 1) * D_MODEL;

    if (tid < 64) {
        *(float4*)&vlog_b[4 * l] = zero4;   // vlog slot 0 = zeros
        sQ[1][l] = qg[D_STATE + l];         // q_1
        sK[0][l] = kg[l];                   // k_0
    }

    float qcur = 0.f, kcur = 0.f, qnx2 = 0.f, knx = 0.f;
    float fa_prev = 0.f;                    // wave0: fa posted at t-1 (== sFA[pc])
    int   n0 = 0, ver0 = 0;                 // wave0: replicated bookkeeping
    if (wv == 0) {
        kcur = kg[l];
        qcur = qg[D_STATE + l];
        knx  = kg[D_STATE + l];
        qnx2 = qg[2 * D_STATE + l];
    }
    float  cnt_l = 0.f;
    int    n = 0, chg_prev = -1, upd_prev = 0;
    float4 vvt = zero4;
    if (wv == 1) vvt = *(const float4*)&vg[4 * l];   // v_0
    const int brow = ((wv - 2) << 5) + (l >> 1);
    const int bh   = l & 1;
    float4 Creg[8];
    float4 tprev[8], kprev[8];
    float  s2prev = 0.f;
    #pragma unroll
    for (int c = 0; c < 8; ++c) { Creg[c] = zero4; tprev[c] = zero4; kprev[c] = zero4; }

    __syncthreads();

    // R30: priority ordering matches criticality ordering.
    if (wv == 1) __builtin_amdgcn_s_setprio(2);
    else if (wv == 0) __builtin_amdgcn_s_setprio(1);

    for (int t = 0; t < TLEN; ++t) {
        const int token = b * TLEN + t;
        const int pc = t & 1, pn = 1 - pc;

        if (wv >= 2) {
            const int  chg  = sFlagChg[pc];
            const bool updf = sFlagUpd[pc] != 0;
            if (chg == brow) {
                const float rn = 1.f / fmaxf(sqrtf(s2prev), 1e-12f);
                #pragma unroll
                for (int c = 0; c < 8; ++c) {
                    Creg[c].x = updf ? tprev[c].x * rn : kprev[c].x;
                    Creg[c].y = updf ? tprev[c].y * rn : kprev[c].y;
                    Creg[c].z = updf ? tprev[c].z * rn : kprev[c].z;
                    Creg[c].w = updf ? tprev[c].w * rn : kprev[c].w;
                }
            }
            const float* qrow = &sQ[pn][32 * bh];
            const float* krow = &sK[pc][32 * bh];
            float pa = 0.f, pb = 0.f, sa = 0.f, sb = 0.f;
            #pragma unroll
            for (int c = 0; c < 8; ++c) {
                const float4 c4 = Creg[c];
                const float4 q4 = *(const float4*)(qrow + 4 * c);
                const float4 k4 = *(const float4*)(krow + 4 * c);
                float4 t4;
                t4.x = 0.9f * c4.x + 0.1f * k4.x;
                t4.y = 0.9f * c4.y + 0.1f * k4.y;
                t4.z = 0.9f * c4.z + 0.1f * k4.z;
                t4.w = 0.9f * c4.w + 0.1f * k4.w;
                if (c < 4) {
                    pa += c4.x * q4.x; pa += c4.y * q4.y;
                    pa += c4.z * q4.z; pa += c4.w * q4.w;
                    sa += t4.x * t4.x; sa += t4.y * t4.y;
                    sa += t4.z * t4.z; sa += t4.w * t4.w;
                } else {
                    pb += c4.x * q4.x; pb += c4.y * q4.y;
                    pb += c4.z * q4.z; pb += c4.w * q4.w;
                    sb += t4.x * t4.x; sb += t4.y * t4.y;
                    sb += t4.z * t4.z; sb += t4.w * t4.w;
                }
                tprev[c] = t4; kprev[c] = k4;
            }
            const float sd  = pa + pb;
            const float dot = sd + dpp_swap1(sd);
            const float ss  = sa + sb;
            const float s2  = ss + dpp_swap1(ss);
            s2prev = s2;
            if (bh == 0) { sBuf[pn][brow] = dot; sS2[pn][brow] = s2; }
        }

        if (wv == 0) {
            // ---- replicated sims/ver/n bookkeeping + stores (R22) ----
            const int chg0 = sFlagChg[pc];
            const int upd0 = sFlagUpd[pc];
            n0  += (chg0 >= 0 && upd0 == 0) ? 1 : 0;     // do_add at t-1
            if (l == chg0) ver0 = t;                     // ver set at t-1 -> t
            const float bufv0 = sBuf[pc][l];
            const int   ip0   = (chg0 < 0) ? 0 : chg0;
            const float s2v0  = sS2[pc][ip0];
            const float bdc0  = bcast_lane(bufv0, ip0);
            const float fupd0 = (0.9f * bdc0 + 0.1f * fa_prev)
                                / fmaxf(sqrtf(s2v0), 1e-12f);
            const float fsim0 = upd0 ? fupd0 : fa_prev;
            const float simv0 = (l == chg0) ? fsim0 : bufv0;
            sims_ws[(size_t)token * MCON + l] = simv0;
            ver_ws[(size_t)token * MCON + l]  = ver0;
            if (l == 0) n_ws[token] = n0;

            // ---- original wave0 work ----
            sQ[pc][l] = qnx2;
            sK[pn][l] = knx;
            const float fa = wave_sum(kcur * qcur);
            if (l == 0) sFA[pn] = fa;
            fa_prev = fa;
            kcur = knx; qcur = qnx2;
            const int tk2 = (t + 2 < TLEN) ? t + 2 : TLEN - 1;
            const int tq3 = (t + 3 < TLEN) ? t + 3 : TLEN - 1;
            knx  = kg[tk2 * D_STATE + l];
            qnx2 = qg[tq3 * D_STATE + l];
        }

        if (wv == 1) {
            // copy arrived v_t out, then issue v_{t+1} load FIRST (R20)
            const float4 vt = vvt;
            const int tk = (t + 1 < TLEN) ? t + 1 : t;
            vvt = *(const float4*)&vg[tk * D_MODEL + 4 * l];

            const int   ip   = (chg_prev < 0) ? 0 : chg_prev;
            const float bufv = sBuf[pc][l];

            // R25: DPP max over bufv lanes (chg_prev masked out) runs in
            // parallel with the fupd chain; fmax is associative -> bit-exact.
            const float lgO = ((l < n && l != chg_prev) ? bufv : NEG_INF) * scale;
            const float mxO = wave_max(lgO);

            const float s2v  = sS2[pc][ip];
            const float fa   = sFA[pc];
            const float bdc  = bcast_lane(bufv, ip);
            const float fupd = (0.9f * bdc + 0.1f * fa)
                               / fmaxf(sqrtf(s2v), 1e-12f);
            const float fsim = upd_prev ? fupd : fa;          // wave-uniform
            const float simv = (l == chg_prev) ? fsim : bufv;

            const float lgC = ((chg_prev >= 0) ? fsim : NEG_INF) * scale;
            const float mx  = fmaxf(mxO, lgC);
            const float lg  = ((l < n) ? simv : NEG_INF) * scale;
            const int   sel    = wave_argmax_fast(lg, mx);
            const float selSim = bcast_lane(simv,  sel);
            const float cnt    = bcast_lane(cnt_l, sel);

            const float4 vs = *(const float4*)&sV[sel * D_MODEL + 4 * l];
            float r = (vs.x - vt.x) * (vs.x - vt.x)
                    + (vs.y - vt.y) * (vs.y - vt.y)
                    + (vs.z - vt.z) * (vs.z - vt.z)
                    + (vs.w - vt.w) * (vs.w - vt.w);
            const float residual = sqrtf(wave_sum(r) * (1.f / 256.f));

            const bool has = n > 0;
            const bool refine = has && (n < MCON) &&
                                (selSim < 0.75f || residual > 1.0f);
            const bool do_add    = ((!has) || refine) && (n < MCON);
            const bool do_update = has && !refine;
            const int  chg = do_update ? sel : n;

            float4 nv;
            nv.x = (vs.x * cnt + vt.x) / (cnt + 1.f);
            nv.y = (vs.y * cnt + vt.y) / (cnt + 1.f);
            nv.z = (vs.z * cnt + vt.z) / (cnt + 1.f);
            nv.w = (vs.w * cnt + vt.w) / (cnt + 1.f);
            float4 valV;
            valV.x = do_update ? nv.x : vt.x;
            valV.y = do_update ? nv.y : vt.y;
            valV.z = do_update ? nv.z : vt.z;
            valV.w = do_update ? nv.w : vt.w;
            *(float4*)&sV[chg * D_MODEL + 4 * l] = valV;
            *(float4*)&vlog_b[(size_t)(t + 1) * D_MODEL + 4 * l] = valV;

            if (l == 0) { sFlagChg[pn] = chg; sFlagUpd[pn] = do_update ? 1 : 0; }

            if (l == sel && do_update) cnt_l = cnt + 1.f;
            if (l == n   && do_add)    cnt_l = 1.f;
            n += do_add ? 1 : 0;
            chg_prev = chg; upd_prev = do_update ? 1 : 0;
        }

        BAR();
    }
}

// ---------------------------------------------------------------------------
// Kernel 3: fused payload, token-tiled (ZT=4 = 1024 blocks, 4/CU). R25-proven.
// ---------------------------------------------------------------------------
__global__ __launch_bounds__(256) void zout_kernel(
    const float* __restrict__ sims_ws, const int* __restrict__ n_ws,
    const int* __restrict__ ver_ws, const float* __restrict__ vlog_ws,
    const float* __restrict__ Wo, const float* __restrict__ bo,
    float* __restrict__ out, const float* __restrict__ ls_p)
{
    const int tok0 = blockIdx.x * ZT;
    const int b    = tok0 >> 10;             // ZT divides TLEN -> same seq
    const int tid  = threadIdx.x;
    const int l    = tid & 63;
    const int wv   = tid >> 6;
    const float scale = fminf(expf(ls_p[0]), 100.f);

    __shared__ float sWt[ZT][MCON];
    __shared__ int   sVer[ZT][MCON];
    __shared__ int   sN[ZT];
    __shared__ float sy[ZT][D_MODEL];

    // softmax + ver loads: wave wv handles token tt = wv (ZT==4)
    for (int tt = wv; tt < ZT; tt += 4) {
        const int token = tok0 + tt;
        const int nt = n_ws[token];
        if (l == 0) sN[tt] = nt;
        sVer[tt][l] = ver_ws[(size_t)token * MCON + l];
        const float simv = sims_ws[(size_t)token * MCON + l];
        const float lg = ((l < nt) ? simv : NEG_INF) * scale;
        const float mx = wave_max(lg);
        const float e  = expf(lg - mx);
        const float sm = wave_sum(e);
        sWt[tt][l] = e / sm;                 // nt==0 -> NaN, guarded below
    }
    __syncthreads();

    const float* base = vlog_ws + (size_t)b * (TLEN + 1) * D_MODEL;
    #pragma unroll
    for (int tt = 0; tt < ZT; ++tt) {
        float z = 0.f;
        const int ntc = sN[tt];
        if (ntc > 0) {
            #pragma unroll 8
            for (int m = 0; m < ntc; ++m) {   // wm==0 exactly for m>=ntc
                const float wm = sWt[tt][m];
                z += wm * base[(size_t)sVer[tt][m] * D_MODEL + tid];
            }
        }
        sy[tt][tid] = z;
    }
    __syncthreads();

    float acc[ZT];
    #pragma unroll
    for (int tt = 0; tt < ZT; ++tt) acc[tt] = 0.f;
    for (int i = 0; i < D_MODEL; ++i) {
        const float wo = Wo[i * D_MODEL + tid];
        #pragma unroll
        for (int tt = 0; tt < ZT; ++tt) acc[tt] += sy[tt][i] * wo;
    }
    const float boi = bo[tid];
    #pragma unroll
    for (int tt = 0; tt < ZT; ++tt)
        out[(size_t)(tok0 + tt) * D_MODEL + tid] = acc[tt] + boi;
}

// ---------------------------------------------------------------------------
extern "C" void kernel_launch(void* const* d_in, const int* in_sizes, int n_in,
                              void* d_out, int out_size, void* d_ws, size_t ws_size,
                              hipStream_t stream)
{
    const float* x  = (const float*)d_in[0];
    const float* Wq = (const float*)d_in[1];
    const float* bq = (const float*)d_in[2];
    const float* Wk = (const float*)d_in[3];
    const float* bk = (const float*)d_in[4];
    const float* Wv = (const float*)d_in[5];
    const float* bv = (const float*)d_in[6];
    const float* Wo = (const float*)d_in[7];
    const float* bo = (const float*)d_in[8];
    const float* ls = (const float*)d_in[9];
    float* out = (float*)d_out;

    const int NTOK = BATCH * TLEN;                 // 4096
    char* ws = (char*)d_ws;
    size_t off = 0;
    float* q_ws    = (float*)(ws + off); off += (size_t)NTOK * D_STATE * 4;
    float* k_ws    = (float*)(ws + off); off += (size_t)NTOK * D_STATE * 4;
    float* v_ws    = (float*)(ws + off); off += (size_t)NTOK * D_MODEL * 4;
    float* sims_ws = (float*)(ws + off); off += (size_t)NTOK * MCON * 4;
    int*   ver_ws  = (int*)  (ws + off); off += (size_t)NTOK * MCON * 4;
    int*   n_ws    = (int*)  (ws + off); off += (size_t)NTOK * 4;
    float* vlog_ws = (float*)(ws + off);

    proj_kernel<<<NTOK / PT, 256, 0, stream>>>(x, Wq, bq, Wk, bk, Wv, bv,
                                               q_ws, k_ws, v_ws);
    scan_kernel<<<BATCH, 256, 0, stream>>>(q_ws, k_ws, v_ws,
                                           sims_ws, n_ws, ver_ws, vlog_ws, ls);
    zout_kernel<<<NTOK / ZT, 256, 0, stream>>>(sims_ws, n_ws, ver_ws, vlog_ws,
                                               Wo, bo, out, ls);
}